// Round 17
// baseline (107.321 us; speedup 1.0000x reference)
//
#include <hip/hip_runtime.h>
#include <hip/hip_bf16.h>

// QueryGrouper: ball_query (first-K-in-index-order within radius) + grouping.
// B=4, N=8192, M=2048, C=128, K=32, radius=0.1, use_xyz from out_size.
//
// R17: BALL VISIBILITY DIAGNOSTIC. Ball stuck at ~25us across three designs
// (Q=1 LDS @32w, Q=2 @16w, Q=4 L2-direct @32w) while the issue-cycle model
// says ~8-12us -- a 3x unexplained factor. This round: R16's ball scan run
// x4 (cnt/ff reset per pass, identical final state, per-pass results kept
// live) -> ball ~100us enters rocprof top-5. VALUBusy>=55% => issue-bound
// (fix: branchless + 2pts/lane); <=35% => stall-bound (fix: decouple/pipeline);
// FETCH>=100MB => L2 misses. Gather: R12-validated one-pass (write roofline).

#define K_NEIGH 32
// f32(0.010000000000000002) — matches JAX weak-typed radius*radius bit-exactly.
#define R2_F32 0.009999999776482582f
#define CCH 128
#define NPTS 8192
#define MQ 2048

// ---- diagnostic ball: R16 structure, scan x4 ----
__global__ __launch_bounds__(256, 8) void ball_split4_diag_kernel(
    const float* __restrict__ xyz,      // (B,3,N)
    const float* __restrict__ new_xyz,  // (B,3,M)
    int* __restrict__ idxb,             // (B*M, K)
    float* __restrict__ out0,           // (B, CO, M, K)
    float* __restrict__ out1,           // (B, 3, M, K)
    int use_xyz)
{
    __shared__ int scnt[4][4];              // [range][query]
    __shared__ int sff [4][4];
    __shared__ int slidx[4][4][K_NEIGH];    // 2 KB

    const int tid  = threadIdx.x;
    const int w    = tid >> 6;         // wave id = point range
    const int lane = tid & 63;
    const int q0 = blockIdx.x * 4;     // 4 queries per block (same batch: 4|2048)
    const int b  = q0 / MQ;
    const int m0 = q0 - b * MQ;

    const float* x0 = xyz + (size_t)b * 3 * NPTS;
    const float* x1 = x0 + NPTS;
    const float* x2 = x1 + NPTS;
    const float* nb = new_xyz + (size_t)b * 3 * MQ;

    float qx[4], qy[4], qz[4];
    #pragma unroll
    for (int j = 0; j < 4; ++j) {
        qx[j] = nb[m0 + j];
        qy[j] = nb[MQ + m0 + j];
        qz[j] = nb[2 * MQ + m0 + j];
    }
    int cnt[4], ff[4];
    const unsigned long long below = (1ull << lane) - 1ull;
    const int rbase = w * 2048;

    for (int pass = 0; pass < 4; ++pass) {
        #pragma unroll
        for (int j = 0; j < 4; ++j) { cnt[j] = 0; ff[j] = 0; }

        for (int g = 0; g < 2048; g += 64) {
            const int i = rbase + g + lane;
            const float ax = x0[i];
            const float ay = x1[i];
            const float az = x2[i];
            #pragma unroll
            for (int j = 0; j < 4; ++j) {
                // match JAX: sub, square (no FMA), left-to-right sum, f32 RN
                const float d2 = __fadd_rn(__fadd_rn(__fmul_rn(ax - qx[j], ax - qx[j]),
                                                     __fmul_rn(ay - qy[j], ay - qy[j])),
                                           __fmul_rn(az - qz[j], az - qz[j]));
                const bool in = d2 < R2_F32;
                const unsigned long long mk = __ballot(in);
                if (mk) {
                    if (cnt[j] == 0) ff[j] = rbase + g + (__ffsll(mk) - 1);
                    if (in) {
                        const int pos = cnt[j] + __popcll(mk & below);
                        if (pos < K_NEIGH) slidx[w][j][pos] = i;
                    }
                    cnt[j] += __popcll(mk);
                }
            }
        }
        // keep this pass's results live (rule #17) so passes 0-2 aren't DCE'd
        asm volatile("" :: "v"(cnt[0] + cnt[1]), "v"(cnt[2] + cnt[3]),
                           "v"(ff[0] + ff[1]),  "v"(ff[2] + ff[3]));
    }

    // publish partial counts/firsts (slidx already in LDS)
    if (lane < 4) {
        scnt[w][lane] = cnt[lane];
        sff [w][lane] = ff[lane];
    }
    __syncthreads();

    // merge: wave w finalizes query w (ranges in index order -> concat[0:K])
    const int jq = w;
    const float qxx = nb[m0 + jq];
    const float qyy = nb[MQ + m0 + jq];
    const float qzz = nb[2 * MQ + m0 + jq];

    if (lane < K_NEIGH) {
        int bacc = 0, jdx = -1, ffq = 0;
        bool ffset = false;
        #pragma unroll
        for (int r = 0; r < 4; ++r) {
            const int cr = scnt[r][jq];
            if (!ffset && cr > 0) { ffq = sff[r][jq]; ffset = true; }
            if (jdx < 0 && lane < bacc + cr) jdx = slidx[r][jq][lane - bacc];
            bacc += cr;
        }
        if (jdx < 0) jdx = ffq;   // fewer than lane+1 hits total (or none -> 0)

        const int m = m0 + jq;
        idxb[((size_t)b * MQ + m) * K_NEIGH + lane] = jdx;
        const float gx = x0[jdx] - qxx;
        const float gy = x1[jdx] - qyy;
        const float gz = x2[jdx] - qzz;
        const size_t MK = (size_t)MQ * K_NEIGH;
        const size_t o1 = (size_t)b * 3 * MK + (size_t)m * K_NEIGH + lane;
        out1[o1]          = gx;
        out1[o1 + MK]     = gy;
        out1[o1 + 2 * MK] = gz;
        if (use_xyz) {
            const size_t o0 = (size_t)b * (CCH + 3) * MK + (size_t)m * K_NEIGH + lane;
            out0[o0]          = gx;
            out0[o0 + MK]     = gy;
            out0[o0 + 2 * MK] = gz;
        }
    }
}

// ---- fallback ball (any shape): global loads, 1 query/wave ----
__global__ __launch_bounds__(256) void ball_query_xyz_kernel(
    const float* __restrict__ xyz, const float* __restrict__ new_xyz,
    int* __restrict__ idxb, float* __restrict__ out0, float* __restrict__ out1,
    int N, int M, int C, int use_xyz)
{
    __shared__ int lidx[4][K_NEIGH];
    const int wave = threadIdx.x >> 6;
    const int lane = threadIdx.x & 63;
    const int q = blockIdx.x * 4 + wave;
    const int b = q / M;
    const int m = q - b * M;

    const float* xb = xyz + (size_t)b * 3 * N;
    const float* x0 = xb;
    const float* x1 = xb + N;
    const float* x2 = xb + 2 * N;
    const float* nb = new_xyz + (size_t)b * 3 * M;
    const float qx = nb[m];
    const float qy = nb[M + m];
    const float qz = nb[2 * M + m];

    int cnt = 0;
    int ff  = 0;
    const unsigned long long below = (1ull << lane) - 1ull;

    for (int t0 = 0; t0 < N; t0 += 64) {
        const int i = t0 + lane;
        const float dx = x0[i] - qx;
        const float dy = x1[i] - qy;
        const float dz = x2[i] - qz;
        const float d2 = __fadd_rn(__fadd_rn(__fmul_rn(dx, dx), __fmul_rn(dy, dy)),
                                   __fmul_rn(dz, dz));
        const bool in_ball = d2 < R2_F32;
        const unsigned long long mask = __ballot(in_ball);
        if (mask) {
            if (cnt == 0) ff = t0 + (__ffsll(mask) - 1);
            if (in_ball) {
                const int pos = cnt + __popcll(mask & below);
                if (pos < K_NEIGH) lidx[wave][pos] = i;
            }
            cnt += __popcll(mask);
            if (cnt >= K_NEIGH) break;
        }
    }

    asm volatile("s_waitcnt lgkmcnt(0)" ::: "memory");

    if (lane < K_NEIGH) {
        const int j = (lane < cnt) ? lidx[wave][lane] : ff;
        idxb[(size_t)q * K_NEIGH + lane] = j;
        const float gx = x0[j] - qx;
        const float gy = x1[j] - qy;
        const float gz = x2[j] - qz;
        const size_t MK = (size_t)M * K_NEIGH;
        const size_t o1 = (size_t)b * 3 * MK + (size_t)m * K_NEIGH + lane;
        out1[o1]          = gx;
        out1[o1 + MK]     = gy;
        out1[o1 + 2 * MK] = gz;
        if (use_xyz) {
            const size_t o0 = (size_t)b * (C + 3) * MK + (size_t)m * K_NEIGH + lane;
            out0[o0]          = gx;
            out0[o0 + MK]     = gy;
            out0[o0 + 2 * MK] = gz;
        }
    }
}

// Fixed geometry: B=4, N=8192, M=2048, C=128. Grid = 256 blocks x 1024 thr.
// One pass, plain float4 stores (R12-validated: runs at write roofline).
__global__ __launch_bounds__(1024, 4) void gather_onepass_kernel(
    const float* __restrict__ feat,  // (B,C,N)
    const int* __restrict__ idxb,    // (B*M,K)
    float* __restrict__ out0,        // (B,CO,M,K)
    int use_xyz)
{
    __shared__ float sf[2 * NPTS];   // 64 KB: [0,N) = ch c0, [N,2N) = ch c0+1

    const int t   = threadIdx.x;
    const int bid = blockIdx.x;
    const int b   = (bid & 7) >> 1;                 // 0..3
    const int cg  = ((bid >> 3) << 1) | (bid & 1);  // 0..63
    const int c0  = cg * 2;

    // ---- Phase A: idx prefetch (regs) + feat stage (LDS) ----
    const int4* ip4 = (const int4*)(idxb + (size_t)b * MQ * K_NEIGH);
    int4 jj[16];
    #pragma unroll
    for (int i = 0; i < 16; ++i) jj[i] = ip4[i * 1024 + t];

    const float4* fv = (const float4*)(feat + ((size_t)b * CCH + c0) * NPTS);
    #pragma unroll
    for (int r = 0; r < 4; ++r)
        ((float4*)sf)[t + r * 1024] = fv[t + r * 1024];
    __syncthreads();

    // ---- Phase B: pure LDS-read + plain float4 stores ----
    const size_t MK = (size_t)MQ * K_NEIGH;
    const int CO   = use_xyz ? (CCH + 3) : CCH;
    const int coff = use_xyz ? 3 : 0;
    float* o0 = out0 + ((size_t)b * CO + coff + c0) * MK;
    float* o1 = o0 + MK;

    #pragma unroll
    for (int i = 0; i < 16; ++i) {
        const int p = i * 4096 + 4 * t;      // flat (m,k) base, k-aligned x4
        const int4 j4 = jj[i];
        float4 s0, s1;
        s0.x = sf[j4.x]; s0.y = sf[j4.y]; s0.z = sf[j4.z]; s0.w = sf[j4.w];
        s1.x = sf[NPTS + j4.x]; s1.y = sf[NPTS + j4.y];
        s1.z = sf[NPTS + j4.z]; s1.w = sf[NPTS + j4.w];
        *(float4*)(o0 + p) = s0;
        *(float4*)(o1 + p) = s1;
    }
}

// Fallback gather (any shape): R1 structure.
__global__ __launch_bounds__(256) void gather_kernel(
    const float* __restrict__ xyz, const float* __restrict__ new_xyz,
    const float* __restrict__ feat, const int* __restrict__ idxb,
    float* __restrict__ out0, float* __restrict__ out1,
    int N, int M, int C, int use_xyz)
{
    const int tid = threadIdx.x;
    const int k = tid & 31;
    const int mloc = tid >> 5;
    const int mchunks = M >> 3;
    const int b = blockIdx.x / mchunks;
    const int m = (blockIdx.x - b * mchunks) * 8 + mloc;
    const int q = b * M + m;
    const int j = idxb[(size_t)q * K_NEIGH + k];
    const size_t xb = (size_t)b * 3 * N;
    const size_t nb = (size_t)b * 3 * M;
    const float gx = xyz[xb + j]         - new_xyz[nb + m];
    const float gy = xyz[xb + N + j]     - new_xyz[nb + M + m];
    const float gz = xyz[xb + 2 * N + j] - new_xyz[nb + 2 * M + m];
    const size_t MK = (size_t)M * K_NEIGH;
    const size_t o1 = (size_t)b * 3 * MK + (size_t)m * K_NEIGH + k;
    out1[o1] = gx; out1[o1 + MK] = gy; out1[o1 + 2 * MK] = gz;
    const int CO = use_xyz ? (C + 3) : C;
    size_t o0 = (size_t)b * CO * MK + (size_t)m * K_NEIGH + k;
    if (use_xyz) {
        out0[o0] = gx; out0[o0 + MK] = gy; out0[o0 + 2 * MK] = gz;
        o0 += 3 * MK;
    }
    const float* fb = feat + (size_t)b * C * N;
    #pragma unroll 4
    for (int c = 0; c < C; c += 4) {
        const float v0 = fb[(size_t)c * N + j];
        const float v1 = fb[(size_t)(c + 1) * N + j];
        const float v2 = fb[(size_t)(c + 2) * N + j];
        const float v3 = fb[(size_t)(c + 3) * N + j];
        out0[o0 + (size_t)c * MK]       = v0;
        out0[o0 + (size_t)(c + 1) * MK] = v1;
        out0[o0 + (size_t)(c + 2) * MK] = v2;
        out0[o0 + (size_t)(c + 3) * MK] = v3;
    }
}

extern "C" void kernel_launch(void* const* d_in, const int* in_sizes, int n_in,
                              void* d_out, int out_size, void* d_ws, size_t ws_size,
                              hipStream_t stream) {
    const float* new_xyz = (const float*)d_in[0];   // (B,3,M)
    const float* xyz     = (const float*)d_in[1];   // (B,3,N)
    const float* feat    = (const float*)d_in[2];   // (B,C,N)

    const int B = 4;                       // fixed by harness setup
    const int M = in_sizes[0] / (3 * B);   // 2048
    const int N = in_sizes[1] / (3 * B);   // 8192
    const int C = in_sizes[2] / (B * N);   // 128

    const long long sz_with = (long long)B * (C + 6) * M * K_NEIGH;
    const int use_xyz = (out_size == sz_with) ? 1 : 0;

    float* out0 = (float*)d_out;
    float* out1 = out0 + (size_t)B * (use_xyz ? (C + 3) : C) * M * K_NEIGH;

    int* idxb = (int*)d_ws;  // B*M*K ints = 1 MB
    const size_t idx_bytes = (size_t)B * M * K_NEIGH * sizeof(int);

    const bool fast = (B == 4) && (N == NPTS) && (M == MQ) && (C == CCH)
                      && (ws_size >= idx_bytes);

    if (fast) {
        ball_split4_diag_kernel<<<(B * MQ) / 4, 256, 0, stream>>>(
            xyz, new_xyz, idxb, out0, out1, use_xyz);
        gather_onepass_kernel<<<256, 1024, 0, stream>>>(feat, idxb, out0, use_xyz);
    } else {
        ball_query_xyz_kernel<<<(B * M) / 4, 256, 0, stream>>>(
            xyz, new_xyz, idxb, out0, out1, N, M, C, use_xyz);
        gather_kernel<<<B * (M / 8), 256, 0, stream>>>(xyz, new_xyz, feat, idxb,
                                                       out0, out1, N, M, C, use_xyz);
    }
}

// Round 18
// 72.050 us; speedup vs baseline: 1.4895x; 1.4895x over previous
//
#include <hip/hip_runtime.h>
#include <hip/hip_bf16.h>

// QueryGrouper: ball_query (first-K-in-index-order within radius) + grouping.
// B=4, N=8192, M=2048, C=128, K=32, radius=0.1, use_xyz from out_size.
//
// R18: lane=query ball. R17 counters: ball issue-bound (VALUBusy 72%, FETCH
// 2.3MB, ~2x the d2-only VALU) -- the overhead is cross-lane hit-ordering
// (ballot/mbcnt/scalar-branch) inherent to lane=point. With lane=query and
// points STREAMED IN INDEX ORDER (uniform scalar loads), ordering is free:
// bookkeeping = lane-local cnt++ + predicated LDS slot write.
// A: 512 blocks(qgroup x quarter) x 16 waves, wave=128pts x 64 queries,
//    slots cap 16/subrange (P(overflow)~1e-18 uniform), in-block concat ->
//    partial {cnt<=32, idx[32]} per (q,quarter) in d_ws.
// B: thread=(q,slot): 4-way concat + pad + idxb + xyz epilogue.
// Gather: R12-validated one-pass (write roofline, FETCH 9.3MB, 6.26TB/s).

#define K_NEIGH 32
// f32(0.010000000000000002) — matches JAX weak-typed radius*radius bit-exactly.
#define R2_F32 0.009999999776482582f
#define CCH 128
#define NPTS 8192
#define MQ 2048

// ---- Kernel A: scan ----
__global__ __launch_bounds__(1024, 8) void ball_scan_kernel(
    const float* __restrict__ xyz,      // (B,3,N)
    const float* __restrict__ new_xyz,  // (B,3,M)
    int* __restrict__ part)             // (B*M, 4, 33)
{
    __shared__ int s_slot[16][64][16];  // 64 KB
    __shared__ int s_cnt[16][64];       // 4 KB

    const int tid  = threadIdx.x;
    const int wv   = __builtin_amdgcn_readfirstlane(tid >> 6);  // SGPR wave id
    const int lane = tid & 63;
    const int qg   = blockIdx.x >> 2;   // 0..127: 64-query group
    const int pr   = blockIdx.x & 3;    // 0..3: 2048-point quarter
    const int b    = qg >> 5;           // batch (qg*64 / 2048)
    const int m    = ((qg & 31) << 6) + lane;

    const float* x0 = xyz + (size_t)b * 3 * NPTS;
    const float* x1 = x0 + NPTS;
    const float* x2 = x1 + NPTS;
    const float* nb = new_xyz + (size_t)b * 3 * MQ;
    const float qx = nb[m];
    const float qy = nb[MQ + m];
    const float qz = nb[2 * MQ + m];

    int cnt = 0;
    const int ibase = pr * 2048 + wv * 128;
    #pragma unroll 8
    for (int p = 0; p < 128; ++p) {
        const int i = ibase + p;        // wave-uniform -> scalar loads
        const float ax = x0[i];
        const float ay = x1[i];
        const float az = x2[i];
        // match JAX: sub, square (no FMA), left-to-right sum, all f32 RN
        const float dx = ax - qx;
        const float dy = ay - qy;
        const float dz = az - qz;
        const float d2 = __fadd_rn(__fadd_rn(__fmul_rn(dx, dx), __fmul_rn(dy, dy)),
                                   __fmul_rn(dz, dz));
        if (d2 < R2_F32) {              // hits arrive in index order per lane
            if (cnt < 16) s_slot[wv][lane][cnt] = i;
            ++cnt;
        }
    }
    s_cnt[wv][lane] = (cnt < 16) ? cnt : 16;
    __syncthreads();

    // in-block merge: thread t -> (q_local = t>>4, k2 = t&15), slots k2, k2+16.
    const int q_local = tid >> 4;
    const int k2 = tid & 15;

    int total = 0;
    #pragma unroll
    for (int w = 0; w < 16; ++w) total += s_cnt[w][q_local];
    const int qcnt = (total < K_NEIGH) ? total : K_NEIGH;

    const int q = (qg << 6) + q_local;
    int* pq = part + ((size_t)q * 4 + pr) * 33;
    if (k2 == 0) pq[0] = qcnt;

    #pragma unroll
    for (int half = 0; half < 2; ++half) {
        const int s = k2 + half * 16;
        if (s < qcnt) {
            int accw = 0, pw = 0, po = 0, found = 0;
            #pragma unroll
            for (int w = 0; w < 16; ++w) {
                const int cw = s_cnt[w][q_local];
                if (!found && s < accw + cw) { pw = w; po = s - accw; found = 1; }
                accw += cw;
            }
            pq[1 + s] = s_slot[pw][q_local][po];
        }
    }
}

// ---- Kernel B: 4-way concat + pad + idx + xyz epilogue ----
__global__ __launch_bounds__(256) void ball_final_kernel(
    const float* __restrict__ xyz, const float* __restrict__ new_xyz,
    const int* __restrict__ part, int* __restrict__ idxb,
    float* __restrict__ out0, float* __restrict__ out1, int use_xyz)
{
    const int t = blockIdx.x * 256 + threadIdx.x;
    const int q = t >> 5;
    const int s = t & 31;
    const int b = q >> 11;              // MQ = 2048
    const int m = q & (MQ - 1);

    const int* P = part + (size_t)q * 4 * 33;
    const int c0 = P[0], c1 = P[33], c2 = P[66], c3 = P[99];
    const int total = c0 + c1 + c2 + c3;

    int j = 0;
    if (total > 0) {
        const int ss = (s < total) ? s : 0;   // pad = merged slot 0 (first hit)
        int pr, off;
        if (ss < c0)                { pr = 0; off = ss; }
        else if (ss < c0 + c1)      { pr = 1; off = ss - c0; }
        else if (ss < c0 + c1 + c2) { pr = 2; off = ss - c0 - c1; }
        else                        { pr = 3; off = ss - c0 - c1 - c2; }
        j = P[pr * 33 + 1 + off];
    }

    idxb[(size_t)q * K_NEIGH + s] = j;

    const float* x0 = xyz + (size_t)b * 3 * NPTS;
    const float* nb = new_xyz + (size_t)b * 3 * MQ;
    const float gx = x0[j]            - nb[m];
    const float gy = x0[NPTS + j]     - nb[MQ + m];
    const float gz = x0[2 * NPTS + j] - nb[2 * MQ + m];
    const size_t MK = (size_t)MQ * K_NEIGH;
    const size_t o1 = (size_t)b * 3 * MK + (size_t)m * K_NEIGH + s;
    out1[o1]          = gx;
    out1[o1 + MK]     = gy;
    out1[o1 + 2 * MK] = gz;
    if (use_xyz) {
        const size_t o0 = (size_t)b * (CCH + 3) * MK + (size_t)m * K_NEIGH + s;
        out0[o0]          = gx;
        out0[o0 + MK]     = gy;
        out0[o0 + 2 * MK] = gz;
    }
}

// ---- fallback ball (any shape): global loads, 1 query/wave ----
__global__ __launch_bounds__(256) void ball_query_xyz_kernel(
    const float* __restrict__ xyz, const float* __restrict__ new_xyz,
    int* __restrict__ idxb, float* __restrict__ out0, float* __restrict__ out1,
    int N, int M, int C, int use_xyz)
{
    __shared__ int lidx[4][K_NEIGH];
    const int wave = threadIdx.x >> 6;
    const int lane = threadIdx.x & 63;
    const int q = blockIdx.x * 4 + wave;
    const int b = q / M;
    const int m = q - b * M;

    const float* xb = xyz + (size_t)b * 3 * N;
    const float* x0 = xb;
    const float* x1 = xb + N;
    const float* x2 = xb + 2 * N;
    const float* nb = new_xyz + (size_t)b * 3 * M;
    const float qx = nb[m];
    const float qy = nb[M + m];
    const float qz = nb[2 * M + m];

    int cnt = 0;
    int ff  = 0;
    const unsigned long long below = (1ull << lane) - 1ull;

    for (int t0 = 0; t0 < N; t0 += 64) {
        const int i = t0 + lane;
        const float dx = x0[i] - qx;
        const float dy = x1[i] - qy;
        const float dz = x2[i] - qz;
        const float d2 = __fadd_rn(__fadd_rn(__fmul_rn(dx, dx), __fmul_rn(dy, dy)),
                                   __fmul_rn(dz, dz));
        const bool in_ball = d2 < R2_F32;
        const unsigned long long mask = __ballot(in_ball);
        if (mask) {
            if (cnt == 0) ff = t0 + (__ffsll(mask) - 1);
            if (in_ball) {
                const int pos = cnt + __popcll(mask & below);
                if (pos < K_NEIGH) lidx[wave][pos] = i;
            }
            cnt += __popcll(mask);
            if (cnt >= K_NEIGH) break;
        }
    }

    asm volatile("s_waitcnt lgkmcnt(0)" ::: "memory");

    if (lane < K_NEIGH) {
        const int j = (lane < cnt) ? lidx[wave][lane] : ff;
        idxb[(size_t)q * K_NEIGH + lane] = j;
        const float gx = x0[j] - qx;
        const float gy = x1[j] - qy;
        const float gz = x2[j] - qz;
        const size_t MK = (size_t)M * K_NEIGH;
        const size_t o1 = (size_t)b * 3 * MK + (size_t)m * K_NEIGH + lane;
        out1[o1]          = gx;
        out1[o1 + MK]     = gy;
        out1[o1 + 2 * MK] = gz;
        if (use_xyz) {
            const size_t o0 = (size_t)b * (C + 3) * MK + (size_t)m * K_NEIGH + lane;
            out0[o0]          = gx;
            out0[o0 + MK]     = gy;
            out0[o0 + 2 * MK] = gz;
        }
    }
}

// Fixed geometry: B=4, N=8192, M=2048, C=128. Grid = 256 blocks x 1024 thr.
// One pass, plain float4 stores (R12-validated: runs at write roofline).
__global__ __launch_bounds__(1024, 4) void gather_onepass_kernel(
    const float* __restrict__ feat,  // (B,C,N)
    const int* __restrict__ idxb,    // (B*M,K)
    float* __restrict__ out0,        // (B,CO,M,K)
    int use_xyz)
{
    __shared__ float sf[2 * NPTS];   // 64 KB: [0,N) = ch c0, [N,2N) = ch c0+1

    const int t   = threadIdx.x;
    const int bid = blockIdx.x;
    const int b   = (bid & 7) >> 1;                 // 0..3
    const int cg  = ((bid >> 3) << 1) | (bid & 1);  // 0..63
    const int c0  = cg * 2;

    // ---- Phase A: idx prefetch (regs) + feat stage (LDS) ----
    const int4* ip4 = (const int4*)(idxb + (size_t)b * MQ * K_NEIGH);
    int4 jj[16];
    #pragma unroll
    for (int i = 0; i < 16; ++i) jj[i] = ip4[i * 1024 + t];

    const float4* fv = (const float4*)(feat + ((size_t)b * CCH + c0) * NPTS);
    #pragma unroll
    for (int r = 0; r < 4; ++r)
        ((float4*)sf)[t + r * 1024] = fv[t + r * 1024];
    __syncthreads();

    // ---- Phase B: pure LDS-read + plain float4 stores ----
    const size_t MK = (size_t)MQ * K_NEIGH;
    const int CO   = use_xyz ? (CCH + 3) : CCH;
    const int coff = use_xyz ? 3 : 0;
    float* o0 = out0 + ((size_t)b * CO + coff + c0) * MK;
    float* o1 = o0 + MK;

    #pragma unroll
    for (int i = 0; i < 16; ++i) {
        const int p = i * 4096 + 4 * t;      // flat (m,k) base, k-aligned x4
        const int4 j4 = jj[i];
        float4 s0, s1;
        s0.x = sf[j4.x]; s0.y = sf[j4.y]; s0.z = sf[j4.z]; s0.w = sf[j4.w];
        s1.x = sf[NPTS + j4.x]; s1.y = sf[NPTS + j4.y];
        s1.z = sf[NPTS + j4.z]; s1.w = sf[NPTS + j4.w];
        *(float4*)(o0 + p) = s0;
        *(float4*)(o1 + p) = s1;
    }
}

// Fallback gather (any shape): R1 structure.
__global__ __launch_bounds__(256) void gather_kernel(
    const float* __restrict__ xyz, const float* __restrict__ new_xyz,
    const float* __restrict__ feat, const int* __restrict__ idxb,
    float* __restrict__ out0, float* __restrict__ out1,
    int N, int M, int C, int use_xyz)
{
    const int tid = threadIdx.x;
    const int k = tid & 31;
    const int mloc = tid >> 5;
    const int mchunks = M >> 3;
    const int b = blockIdx.x / mchunks;
    const int m = (blockIdx.x - b * mchunks) * 8 + mloc;
    const int q = b * M + m;
    const int j = idxb[(size_t)q * K_NEIGH + k];
    const size_t xb = (size_t)b * 3 * N;
    const size_t nb = (size_t)b * 3 * M;
    const float gx = xyz[xb + j]         - new_xyz[nb + m];
    const float gy = xyz[xb + N + j]     - new_xyz[nb + M + m];
    const float gz = xyz[xb + 2 * N + j] - new_xyz[nb + 2 * M + m];
    const size_t MK = (size_t)M * K_NEIGH;
    const size_t o1 = (size_t)b * 3 * MK + (size_t)m * K_NEIGH + k;
    out1[o1] = gx; out1[o1 + MK] = gy; out1[o1 + 2 * MK] = gz;
    const int CO = use_xyz ? (C + 3) : C;
    size_t o0 = (size_t)b * CO * MK + (size_t)m * K_NEIGH + k;
    if (use_xyz) {
        out0[o0] = gx; out0[o0 + MK] = gy; out0[o0 + 2 * MK] = gz;
        o0 += 3 * MK;
    }
    const float* fb = feat + (size_t)b * C * N;
    #pragma unroll 4
    for (int c = 0; c < C; c += 4) {
        const float v0 = fb[(size_t)c * N + j];
        const float v1 = fb[(size_t)(c + 1) * N + j];
        const float v2 = fb[(size_t)(c + 2) * N + j];
        const float v3 = fb[(size_t)(c + 3) * N + j];
        out0[o0 + (size_t)c * MK]       = v0;
        out0[o0 + (size_t)(c + 1) * MK] = v1;
        out0[o0 + (size_t)(c + 2) * MK] = v2;
        out0[o0 + (size_t)(c + 3) * MK] = v3;
    }
}

extern "C" void kernel_launch(void* const* d_in, const int* in_sizes, int n_in,
                              void* d_out, int out_size, void* d_ws, size_t ws_size,
                              hipStream_t stream) {
    const float* new_xyz = (const float*)d_in[0];   // (B,3,M)
    const float* xyz     = (const float*)d_in[1];   // (B,3,N)
    const float* feat    = (const float*)d_in[2];   // (B,C,N)

    const int B = 4;                       // fixed by harness setup
    const int M = in_sizes[0] / (3 * B);   // 2048
    const int N = in_sizes[1] / (3 * B);   // 8192
    const int C = in_sizes[2] / (B * N);   // 128

    const long long sz_with = (long long)B * (C + 6) * M * K_NEIGH;
    const int use_xyz = (out_size == sz_with) ? 1 : 0;

    float* out0 = (float*)d_out;
    float* out1 = out0 + (size_t)B * (use_xyz ? (C + 3) : C) * M * K_NEIGH;

    int* idxb = (int*)d_ws;                         // B*M*K ints = 1 MB
    const size_t idx_bytes  = (size_t)B * M * K_NEIGH * sizeof(int);
    int* part = (int*)((char*)d_ws + idx_bytes);    // B*M*4*33 ints = 4.3 MB
    const size_t part_bytes = (size_t)B * M * 4 * 33 * sizeof(int);

    const bool fast = (B == 4) && (N == NPTS) && (M == MQ) && (C == CCH)
                      && (ws_size >= idx_bytes + part_bytes);

    if (fast) {
        ball_scan_kernel<<<512, 1024, 0, stream>>>(xyz, new_xyz, part);
        ball_final_kernel<<<(B * MQ * K_NEIGH) / 256, 256, 0, stream>>>(
            xyz, new_xyz, part, idxb, out0, out1, use_xyz);
        gather_onepass_kernel<<<256, 1024, 0, stream>>>(feat, idxb, out0, use_xyz);
    } else {
        ball_query_xyz_kernel<<<(B * M) / 4, 256, 0, stream>>>(
            xyz, new_xyz, idxb, out0, out1, N, M, C, use_xyz);
        gather_kernel<<<B * (M / 8), 256, 0, stream>>>(xyz, new_xyz, feat, idxb,
                                                       out0, out1, N, M, C, use_xyz);
    }
}

// Round 19
// 53.709 us; speedup vs baseline: 1.9982x; 1.3415x over previous
//
#include <hip/hip_runtime.h>
#include <hip/hip_bf16.h>

// QueryGrouper: ball_query (first-K-in-index-order within radius) + grouping.
// B=4, N=8192, M=2048, C=128, K=32, radius=0.1, use_xyz from out_size.
//
// R19: R16 ball (lane=point, Q=4 x 4-range split, 32 w/CU — best measured 25us,
// VALUBusy 72%, 2445 VALU/wave vs 1250 d2-floor) with the bookkeeping fat cut:
// (1) ff first-hit tracking DELETED from scan — pad value == slot 0 of first
//     non-empty range, already in LDS at merge time;
// (2) ballot fed directly from the compare (no bool materialization);
// (3) cnt updated unconditionally via scalar popcount (SALU, off the VALU pipe).
// ~1600 VALU/wave predicted -> ball ~16-18us. Gather: R12-validated one-pass
// (write roofline: FETCH 9.3MB, 6.26 TB/s). R18's lane=query scan (40us,
// serial scalar-load chain + per-point divergence) abandoned.

#define K_NEIGH 32
// f32(0.010000000000000002) — matches JAX weak-typed radius*radius bit-exactly.
#define R2_F32 0.009999999776482582f
#define CCH 128
#define NPTS 8192
#define MQ 2048

// ---- fast-path ball: 256 thr = 4 waves; wave w = point range w*2048..+2048,
// all 4 waves share the block's 4 queries; 4-way ordered merge in LDS ----
__global__ __launch_bounds__(256, 8) void ball_split4_kernel(
    const float* __restrict__ xyz,      // (B,3,N)
    const float* __restrict__ new_xyz,  // (B,3,M)
    int* __restrict__ idxb,             // (B*M, K)
    float* __restrict__ out0,           // (B, CO, M, K)
    float* __restrict__ out1,           // (B, 3, M, K)
    int use_xyz)
{
    __shared__ int scnt[4][4];              // [range][query]
    __shared__ int slidx[4][4][K_NEIGH];    // 2 KB

    const int tid  = threadIdx.x;
    const int w    = tid >> 6;         // wave id = point range
    const int lane = tid & 63;
    const int q0 = blockIdx.x * 4;     // 4 queries per block (same batch: 4|2048)
    const int b  = q0 / MQ;
    const int m0 = q0 - b * MQ;

    const float* x0 = xyz + (size_t)b * 3 * NPTS;
    const float* x1 = x0 + NPTS;
    const float* x2 = x1 + NPTS;
    const float* nb = new_xyz + (size_t)b * 3 * MQ;

    float qx[4], qy[4], qz[4];
    #pragma unroll
    for (int j = 0; j < 4; ++j) {
        qx[j] = nb[m0 + j];
        qy[j] = nb[MQ + m0 + j];
        qz[j] = nb[2 * MQ + m0 + j];
    }
    int cnt[4] = {0, 0, 0, 0};
    const unsigned long long below = (1ull << lane) - 1ull;

    const int rbase = w * 2048;
    #pragma unroll 2
    for (int g = 0; g < 2048; g += 64) {
        const int i = rbase + g + lane;
        const float ax = x0[i];
        const float ay = x1[i];
        const float az = x2[i];
        #pragma unroll
        for (int j = 0; j < 4; ++j) {
            // match JAX: sub, square (no FMA), left-to-right sum, all f32 RN
            const float d2 = __fadd_rn(__fadd_rn(__fmul_rn(ax - qx[j], ax - qx[j]),
                                                 __fmul_rn(ay - qy[j], ay - qy[j])),
                                       __fmul_rn(az - qz[j], az - qz[j]));
            // ballot fed directly from the compare; mask lives in SGPRs
            const unsigned long long mk = __ballot(d2 < R2_F32);
            if (d2 < R2_F32) {               // only truly divergent part
                const int pos = cnt[j] + (int)__popcll(mk & below);
                if (pos < K_NEIGH) slidx[w][j][pos] = i;
            }
            cnt[j] += (int)__popcll(mk);     // scalar s_bcnt1 (SALU pipe)
        }
    }

    // publish partial counts (slidx already in LDS)
    if (lane < 4) scnt[w][lane] = cnt[lane];
    __syncthreads();

    // merge: wave w finalizes query w. Ranges are in index order, so the
    // final list = concat(range lists)[0:K]; pad = slot 0 of first non-empty
    // range (= first hit overall), or 0 if no hits anywhere.
    const int jq = w;                   // 4 waves, 4 queries
    const float qxx = nb[m0 + jq];
    const float qyy = nb[MQ + m0 + jq];
    const float qzz = nb[2 * MQ + m0 + jq];

    if (lane < K_NEIGH) {
        int bacc = 0, jdx = -1, ffq = 0;
        bool ffset = false;
        #pragma unroll
        for (int r = 0; r < 4; ++r) {
            const int cr = scnt[r][jq];
            if (!ffset && cr > 0) { ffq = slidx[r][jq][0]; ffset = true; }
            if (jdx < 0 && lane < bacc + cr) jdx = slidx[r][jq][lane - bacc];
            bacc += cr;
        }
        if (jdx < 0) jdx = ffq;   // fewer than lane+1 hits total (or none -> 0)

        const int m = m0 + jq;
        idxb[((size_t)b * MQ + m) * K_NEIGH + lane] = jdx;
        const float gx = x0[jdx] - qxx;
        const float gy = x1[jdx] - qyy;
        const float gz = x2[jdx] - qzz;
        const size_t MK = (size_t)MQ * K_NEIGH;
        const size_t o1 = (size_t)b * 3 * MK + (size_t)m * K_NEIGH + lane;
        out1[o1]          = gx;
        out1[o1 + MK]     = gy;
        out1[o1 + 2 * MK] = gz;
        if (use_xyz) {
            const size_t o0 = (size_t)b * (CCH + 3) * MK + (size_t)m * K_NEIGH + lane;
            out0[o0]          = gx;
            out0[o0 + MK]     = gy;
            out0[o0 + 2 * MK] = gz;
        }
    }
}

// ---- fallback ball (any shape): global loads, 1 query/wave ----
__global__ __launch_bounds__(256) void ball_query_xyz_kernel(
    const float* __restrict__ xyz, const float* __restrict__ new_xyz,
    int* __restrict__ idxb, float* __restrict__ out0, float* __restrict__ out1,
    int N, int M, int C, int use_xyz)
{
    __shared__ int lidx[4][K_NEIGH];
    const int wave = threadIdx.x >> 6;
    const int lane = threadIdx.x & 63;
    const int q = blockIdx.x * 4 + wave;
    const int b = q / M;
    const int m = q - b * M;

    const float* xb = xyz + (size_t)b * 3 * N;
    const float* x0 = xb;
    const float* x1 = xb + N;
    const float* x2 = xb + 2 * N;
    const float* nb = new_xyz + (size_t)b * 3 * M;
    const float qx = nb[m];
    const float qy = nb[M + m];
    const float qz = nb[2 * M + m];

    int cnt = 0;
    int ff  = 0;
    const unsigned long long below = (1ull << lane) - 1ull;

    for (int t0 = 0; t0 < N; t0 += 64) {
        const int i = t0 + lane;
        const float dx = x0[i] - qx;
        const float dy = x1[i] - qy;
        const float dz = x2[i] - qz;
        const float d2 = __fadd_rn(__fadd_rn(__fmul_rn(dx, dx), __fmul_rn(dy, dy)),
                                   __fmul_rn(dz, dz));
        const bool in_ball = d2 < R2_F32;
        const unsigned long long mask = __ballot(in_ball);
        if (mask) {
            if (cnt == 0) ff = t0 + (__ffsll(mask) - 1);
            if (in_ball) {
                const int pos = cnt + __popcll(mask & below);
                if (pos < K_NEIGH) lidx[wave][pos] = i;
            }
            cnt += __popcll(mask);
            if (cnt >= K_NEIGH) break;
        }
    }

    asm volatile("s_waitcnt lgkmcnt(0)" ::: "memory");

    if (lane < K_NEIGH) {
        const int j = (lane < cnt) ? lidx[wave][lane] : ff;
        idxb[(size_t)q * K_NEIGH + lane] = j;
        const float gx = x0[j] - qx;
        const float gy = x1[j] - qy;
        const float gz = x2[j] - qz;
        const size_t MK = (size_t)M * K_NEIGH;
        const size_t o1 = (size_t)b * 3 * MK + (size_t)m * K_NEIGH + lane;
        out1[o1]          = gx;
        out1[o1 + MK]     = gy;
        out1[o1 + 2 * MK] = gz;
        if (use_xyz) {
            const size_t o0 = (size_t)b * (C + 3) * MK + (size_t)m * K_NEIGH + lane;
            out0[o0]          = gx;
            out0[o0 + MK]     = gy;
            out0[o0 + 2 * MK] = gz;
        }
    }
}

// Fixed geometry: B=4, N=8192, M=2048, C=128. Grid = 256 blocks x 1024 thr.
// One pass, plain float4 stores (R12-validated: runs at write roofline).
__global__ __launch_bounds__(1024, 4) void gather_onepass_kernel(
    const float* __restrict__ feat,  // (B,C,N)
    const int* __restrict__ idxb,    // (B*M,K)
    float* __restrict__ out0,        // (B,CO,M,K)
    int use_xyz)
{
    __shared__ float sf[2 * NPTS];   // 64 KB: [0,N) = ch c0, [N,2N) = ch c0+1

    const int t   = threadIdx.x;
    const int bid = blockIdx.x;
    const int b   = (bid & 7) >> 1;                 // 0..3
    const int cg  = ((bid >> 3) << 1) | (bid & 1);  // 0..63
    const int c0  = cg * 2;

    // ---- Phase A: idx prefetch (regs) + feat stage (LDS) ----
    const int4* ip4 = (const int4*)(idxb + (size_t)b * MQ * K_NEIGH);
    int4 jj[16];
    #pragma unroll
    for (int i = 0; i < 16; ++i) jj[i] = ip4[i * 1024 + t];

    const float4* fv = (const float4*)(feat + ((size_t)b * CCH + c0) * NPTS);
    #pragma unroll
    for (int r = 0; r < 4; ++r)
        ((float4*)sf)[t + r * 1024] = fv[t + r * 1024];
    __syncthreads();

    // ---- Phase B: pure LDS-read + plain float4 stores ----
    const size_t MK = (size_t)MQ * K_NEIGH;
    const int CO   = use_xyz ? (CCH + 3) : CCH;
    const int coff = use_xyz ? 3 : 0;
    float* o0 = out0 + ((size_t)b * CO + coff + c0) * MK;
    float* o1 = o0 + MK;

    #pragma unroll
    for (int i = 0; i < 16; ++i) {
        const int p = i * 4096 + 4 * t;      // flat (m,k) base, k-aligned x4
        const int4 j4 = jj[i];
        float4 s0, s1;
        s0.x = sf[j4.x]; s0.y = sf[j4.y]; s0.z = sf[j4.z]; s0.w = sf[j4.w];
        s1.x = sf[NPTS + j4.x]; s1.y = sf[NPTS + j4.y];
        s1.z = sf[NPTS + j4.z]; s1.w = sf[NPTS + j4.w];
        *(float4*)(o0 + p) = s0;
        *(float4*)(o1 + p) = s1;
    }
}

// Fallback gather (any shape): R1 structure.
__global__ __launch_bounds__(256) void gather_kernel(
    const float* __restrict__ xyz, const float* __restrict__ new_xyz,
    const float* __restrict__ feat, const int* __restrict__ idxb,
    float* __restrict__ out0, float* __restrict__ out1,
    int N, int M, int C, int use_xyz)
{
    const int tid = threadIdx.x;
    const int k = tid & 31;
    const int mloc = tid >> 5;
    const int mchunks = M >> 3;
    const int b = blockIdx.x / mchunks;
    const int m = (blockIdx.x - b * mchunks) * 8 + mloc;
    const int q = b * M + m;
    const int j = idxb[(size_t)q * K_NEIGH + k];
    const size_t xb = (size_t)b * 3 * N;
    const size_t nb = (size_t)b * 3 * M;
    const float gx = xyz[xb + j]         - new_xyz[nb + m];
    const float gy = xyz[xb + N + j]     - new_xyz[nb + M + m];
    const float gz = xyz[xb + 2 * N + j] - new_xyz[nb + 2 * M + m];
    const size_t MK = (size_t)M * K_NEIGH;
    const size_t o1 = (size_t)b * 3 * MK + (size_t)m * K_NEIGH + k;
    out1[o1] = gx; out1[o1 + MK] = gy; out1[o1 + 2 * MK] = gz;
    const int CO = use_xyz ? (C + 3) : C;
    size_t o0 = (size_t)b * CO * MK + (size_t)m * K_NEIGH + k;
    if (use_xyz) {
        out0[o0] = gx; out0[o0 + MK] = gy; out0[o0 + 2 * MK] = gz;
        o0 += 3 * MK;
    }
    const float* fb = feat + (size_t)b * C * N;
    #pragma unroll 4
    for (int c = 0; c < C; c += 4) {
        const float v0 = fb[(size_t)c * N + j];
        const float v1 = fb[(size_t)(c + 1) * N + j];
        const float v2 = fb[(size_t)(c + 2) * N + j];
        const float v3 = fb[(size_t)(c + 3) * N + j];
        out0[o0 + (size_t)c * MK]       = v0;
        out0[o0 + (size_t)(c + 1) * MK] = v1;
        out0[o0 + (size_t)(c + 2) * MK] = v2;
        out0[o0 + (size_t)(c + 3) * MK] = v3;
    }
}

extern "C" void kernel_launch(void* const* d_in, const int* in_sizes, int n_in,
                              void* d_out, int out_size, void* d_ws, size_t ws_size,
                              hipStream_t stream) {
    const float* new_xyz = (const float*)d_in[0];   // (B,3,M)
    const float* xyz     = (const float*)d_in[1];   // (B,3,N)
    const float* feat    = (const float*)d_in[2];   // (B,C,N)

    const int B = 4;                       // fixed by harness setup
    const int M = in_sizes[0] / (3 * B);   // 2048
    const int N = in_sizes[1] / (3 * B);   // 8192
    const int C = in_sizes[2] / (B * N);   // 128

    const long long sz_with = (long long)B * (C + 6) * M * K_NEIGH;
    const int use_xyz = (out_size == sz_with) ? 1 : 0;

    float* out0 = (float*)d_out;
    float* out1 = out0 + (size_t)B * (use_xyz ? (C + 3) : C) * M * K_NEIGH;

    int* idxb = (int*)d_ws;  // B*M*K ints = 1 MB
    const size_t idx_bytes = (size_t)B * M * K_NEIGH * sizeof(int);

    const bool fast = (B == 4) && (N == NPTS) && (M == MQ) && (C == CCH)
                      && (ws_size >= idx_bytes);

    if (fast) {
        ball_split4_kernel<<<(B * MQ) / 4, 256, 0, stream>>>(
            xyz, new_xyz, idxb, out0, out1, use_xyz);
        gather_onepass_kernel<<<256, 1024, 0, stream>>>(feat, idxb, out0, use_xyz);
    } else {
        ball_query_xyz_kernel<<<(B * M) / 4, 256, 0, stream>>>(
            xyz, new_xyz, idxb, out0, out1, N, M, C, use_xyz);
        gather_kernel<<<B * (M / 8), 256, 0, stream>>>(xyz, new_xyz, feat, idxb,
                                                       out0, out1, N, M, C, use_xyz);
    }
}